// Round 11
// baseline (143.897 us; speedup 1.0000x reference)
//
#include <hip/hip_runtime.h>
#include <hip/hip_bf16.h>

#define NN   8192
#define INF_ 256
#define OUTF 128
#define SLOPE 0.2f
#define NJC  8               // j-chunks
#define JCHUNK (NN / NJC)    // 1024
#define NSUB 8               // subs per chunk (128 j each)

typedef float f32x4  __attribute__((ext_vector_type(4)));
typedef float f32x16 __attribute__((ext_vector_type(16)));
typedef short bf16x8 __attribute__((ext_vector_type(8)));
typedef int   i32x4  __attribute__((ext_vector_type(4)));
typedef unsigned int u32;
typedef unsigned short u16;
typedef u16 u16x2 __attribute__((ext_vector_type(2)));

__device__ __forceinline__ u16 f2bf(float f) {
  return __builtin_bit_cast(u16, __float2bfloat16(f));
}

// j mapping (tile-major): j = jc*1024 + tt*64 + pr*8 + e, pr = 2w+g.
// jg = j>>3 = jc*128 + tt*8 + pr  ->  hbF is PLAIN jg-order:
//   hbF[((jg*4 + c)*32 + x)*8 + e]   (c = col>>5, x = col&31)

// ---------------------------------------------------------------------------
// K1: h = X @ W (fp32). 512 blocks x 16 rows x 256 thr (2 blocks/CU).
// Writes hbF (bf16 B-frag order), s1, s2.
// ---------------------------------------------------------------------------
__global__ __launch_bounds__(256) void gat_k1(
    const float* __restrict__ X, const float* __restrict__ W,
    const float* __restrict__ a, u16* __restrict__ hbF,
    float* __restrict__ s1, float* __restrict__ s2) {
  __shared__ float xs[16 * INF_];
  const int t = threadIdx.x;
  const int r0 = blockIdx.x * 16;
  {
    const f32x4* src = (const f32x4*)(X + (size_t)r0 * INF_);
    f32x4* dst = (f32x4*)xs;
#pragma unroll
    for (int i = 0; i < 4; i++) dst[t + 256 * i] = src[t + 256 * i];
  }
  __syncthreads();
  const int cg = t & 31;   // 4-col group
  const int rg = t >> 5;   // 2-row group (0..7)
  float acc[2][4];
#pragma unroll
  for (int i = 0; i < 2; i++)
#pragma unroll
    for (int j = 0; j < 4; j++) acc[i][j] = 0.f;

  for (int k = 0; k < INF_; k += 4) {
    f32x4 xv[2];
#pragma unroll
    for (int i = 0; i < 2; i++) xv[i] = *(const f32x4*)&xs[(rg * 2 + i) * INF_ + k];
#pragma unroll
    for (int kk = 0; kk < 4; kk++) {
      f32x4 wv = *(const f32x4*)&W[(k + kk) * OUTF + cg * 4];
#pragma unroll
      for (int i = 0; i < 2; i++)
#pragma unroll
        for (int j = 0; j < 4; j++) acc[i][j] = fmaf(xv[i][kk], wv[j], acc[i][j]);
    }
  }

  f32x4 a1v = *(const f32x4*)&a[cg * 4];
  f32x4 a2v = *(const f32x4*)&a[OUTF + cg * 4];
  float p1[2], p2[2];
#pragma unroll
  for (int i = 0; i < 2; i++) {
    p1[i] = acc[i][0] * a1v[0] + acc[i][1] * a1v[1] + acc[i][2] * a1v[2] + acc[i][3] * a1v[3];
    p2[i] = acc[i][0] * a2v[0] + acc[i][1] * a2v[1] + acc[i][2] * a2v[2] + acc[i][3] * a2v[3];
  }
#pragma unroll
  for (int m = 1; m < 32; m <<= 1) {
#pragma unroll
    for (int i = 0; i < 2; i++) {
      p1[i] += __shfl_xor(p1[i], m);
      p2[i] += __shfl_xor(p2[i], m);
    }
  }
  if (cg == 0) {
#pragma unroll
    for (int i = 0; i < 2; i++) {
      s1[r0 + rg * 2 + i] = p1[i];
      s2[r0 + rg * 2 + i] = p2[i];
    }
  }

  const int R0 = r0 + rg * 2;
  const int jg = R0 >> 3;
  const int e0 = R0 & 7;   // even
#pragma unroll
  for (int j = 0; j < 4; j++) {
    const int C = cg * 4 + j;
    u16x2 pk = {f2bf(acc[0][j]), f2bf(acc[1][j])};
    *(u16x2*)(hbF + ((size_t)(jg * 4 + (C >> 5)) * 32 + (C & 31)) * 8 + e0) = pk;
  }
}

// ---------------------------------------------------------------------------
// K2: E1 = exp(s2); E2 = exp(SLOPE*s2); bmax[block] = max chunk.
// ---------------------------------------------------------------------------
__global__ __launch_bounds__(256) void gat_k2(const float* __restrict__ s2,
                                              float* __restrict__ bmax,
                                              float* __restrict__ E1,
                                              float* __restrict__ E2) {
  __shared__ float sm[4];
  const int t = threadIdx.x;
  const int i = blockIdx.x * 256 + t;
  f32x4 v = ((const f32x4*)s2)[i];
  f32x4 e1, e2;
  float m = -1e30f;
#pragma unroll
  for (int k = 0; k < 4; k++) {
    m = fmaxf(m, v[k]);
    e1[k] = __expf(v[k]);
    e2[k] = __expf(SLOPE * v[k]);
  }
  ((f32x4*)E1)[i] = e1;
  ((f32x4*)E2)[i] = e2;
#pragma unroll
  for (int k = 1; k < 64; k <<= 1) m = fmaxf(m, __shfl_xor(m, k));
  if ((t & 63) == 0) sm[t >> 6] = m;
  __syncthreads();
  if (t == 0)
    bmax[blockIdx.x] = fmaxf(fmaxf(sm[0], sm[1]), fmaxf(sm[2], sm[3]));
}

// ---------------------------------------------------------------------------
// K3: fused adj-stream + mask + lrelu + softmax-num + PV, 32 rows x 1024 j.
// Sub-pipelined: 8 subs of 128 j; per iter {pack s+1 -> LDS, issue loads
// s+2, compute 2 tiles, lgkm-only barrier}. adj loads stay in flight
// across barriers (no vmcnt drain). 4 waves, 4 blocks/CU (16 waves).
// ---------------------------------------------------------------------------
__device__ __forceinline__ void st16(float* dst, const f32x16& A, int g) {
#pragma unroll
  for (int r = 0; r < 16; r++) {
    const int dr = (r & 3) + 8 * (r >> 2) + 4 * g;
    dst[dr * 128] = A[r];
  }
}
__device__ __forceinline__ void ad16(float* dst, const f32x16& A, int g) {
#pragma unroll
  for (int r = 0; r < 16; r++) {
    const int dr = (r & 3) + 8 * (r >> 2) + 4 * g;
    dst[dr * 128] += A[r];
  }
}

__global__ __launch_bounds__(256, 4) void gat_k3(
    const int* __restrict__ adj, const u16* __restrict__ hbF,
    const float* __restrict__ s1g, const float* __restrict__ E1,
    const float* __restrict__ E2, const float* __restrict__ bmax,
    float* __restrict__ part, float* __restrict__ dpart) {
  __shared__ unsigned char mbits[4096];  // 8 subs x 512 B (32 rows x 16 jg)
  __shared__ float lred[8192];           // 32 KB: 2 reduce bufs
  __shared__ float dred[128];
  const int t = threadIdx.x;
  const int w = t >> 6;        // 0..3
  const int l = t & 63;
  const int rb = blockIdx.x & 255;
  const int jc = blockIdx.x >> 8;   // 0..7
  const int r0 = rb * 32;
  const int row = l & 31;
  const int g = l >> 5;
  const int x = l & 31;
  const int pr = 2 * w + g;    // this lane's k-slice (0..7)

  // ---- per-row constants ----
  float s2m = bmax[0];
#pragma unroll
  for (int k = 1; k < 8; k++) s2m = fmaxf(s2m, bmax[k]);
  const float s1r = s1g[r0 + row];
  float Mi = s1r + s2m;
  Mi = fmaxf(Mi, SLOPE * Mi);
  const float A = __expf(s1r - Mi);
  const float B = __expf(SLOPE * s1r - Mi);

  // ---- staging ids: thread (srow = t>>3, q = t&7) covers 2 jg per sub ----
  const int srow = t >> 3;
  const int q = t & 7;
  const int* gsrc = adj + (size_t)(r0 + srow) * NN + jc * JCHUNK + q * 16;

  i32x4 st[4];
#define LOADS(S)                                   \
  {                                                \
    const int* p_ = gsrc + (S) * 128;              \
    st[0] = *(const i32x4*)(p_);                   \
    st[1] = *(const i32x4*)(p_ + 4);               \
    st[2] = *(const i32x4*)(p_ + 8);               \
    st[3] = *(const i32x4*)(p_ + 12);              \
  }
#define PACKW(S)                                                         \
  {                                                                      \
    unsigned b0 = 0, b1 = 0;                                             \
    _Pragma("unroll") for (int e = 0; e < 4; e++) {                      \
      b0 |= (st[0][e] > 0 ? 1u : 0u) << e;                               \
      b0 |= (st[1][e] > 0 ? 1u : 0u) << (e + 4);                         \
      b1 |= (st[2][e] > 0 ? 1u : 0u) << e;                               \
      b1 |= (st[3][e] > 0 ? 1u : 0u) << (e + 4);                         \
    }                                                                    \
    *(u16*)&mbits[(S) * 512 + srow * 16 + q * 2] = (u16)(b0 | (b1 << 8));\
  }

  f32x16 acc0 = 0.f, acc1 = 0.f, acc2 = 0.f, acc3 = 0.f;
  float dsA = 0.f, dsB = 0.f;

  // ---- prologue ----
  LOADS(0);
  PACKW(0);
  LOADS(1);
  asm volatile("s_waitcnt lgkmcnt(0)" ::: "memory");
  __builtin_amdgcn_s_barrier();

  for (int s = 0; s < NSUB; s++) {
    if (s + 1 < NSUB) PACKW(s + 1);     // waits vmcnt(st); ds_write region s+1
    if (s + 2 < NSUB) LOADS(s + 2);     // issue next-next; stays in flight

#pragma unroll
    for (int u = 0; u < 2; u++) {
      const int tt = 2 * s + u;
      const unsigned b = mbits[s * 512 + row * 16 + u * 8 + pr];
      const int jg = jc * 128 + tt * 8 + pr;
      const u16* bqb = hbF + (size_t)jg * 4 * 256 + x * 8;
      bf16x8 b0 = *(const bf16x8*)(bqb);
      bf16x8 b1 = *(const bf16x8*)(bqb + 256);
      bf16x8 b2 = *(const bf16x8*)(bqb + 512);
      bf16x8 b3 = *(const bf16x8*)(bqb + 768);
      const int j0 = jc * JCHUNK + tt * 64 + pr * 8;
      f32x4 u0 = *(const f32x4*)(E1 + j0);
      f32x4 u1 = *(const f32x4*)(E1 + j0 + 4);
      f32x4 v0 = *(const f32x4*)(E2 + j0);
      f32x4 v1 = *(const f32x4*)(E2 + j0 + 4);
      const float uu[8] = {u0[0], u0[1], u0[2], u0[3], u1[0], u1[1], u1[2], u1[3]};
      const float vv[8] = {v0[0], v0[1], v0[2], v0[3], v1[0], v1[1], v1[2], v1[3]};

      u32 aw[4];
#pragma unroll
      for (int e = 0; e < 8; e += 2) {
        float pa = fmaxf(A * uu[e],     B * vv[e]);
        float pb = fmaxf(A * uu[e + 1], B * vv[e + 1]);
        pa = (b & (1u << e))       ? pa : 0.f;
        pb = (b & (1u << (e + 1))) ? pb : 0.f;
        dsA += pa;
        dsB += pb;
        aw[e >> 1] = __builtin_amdgcn_perm(
            __builtin_bit_cast(u32, pb) + 0x8000u,
            __builtin_bit_cast(u32, pa) + 0x8000u, 0x07060302u);
      }
      const bf16x8 af =
          __builtin_bit_cast(bf16x8, (i32x4){(int)aw[0], (int)aw[1],
                                             (int)aw[2], (int)aw[3]});
      acc0 = __builtin_amdgcn_mfma_f32_32x32x16_bf16(af, b0, acc0, 0, 0, 0);
      acc1 = __builtin_amdgcn_mfma_f32_32x32x16_bf16(af, b1, acc1, 0, 0, 0);
      acc2 = __builtin_amdgcn_mfma_f32_32x32x16_bf16(af, b2, acc2, 0, 0, 0);
      acc3 = __builtin_amdgcn_mfma_f32_32x32x16_bf16(af, b3, acc3, 0, 0, 0);
    }

    // order LDS only: adj global loads remain in flight across the barrier
    asm volatile("s_waitcnt lgkmcnt(0)" ::: "memory");
    __builtin_amdgcn_s_barrier();
  }

  // ---- denominator partial ----
  float dsum = dsA + dsB;
  dsum += __shfl_xor(dsum, 32);
  if (l < 32) dred[w * 32 + l] = dsum;

  // ---- accumulator reduce: 4 waves -> 2 bufs -> sum ----
  const int colw = l & 31;
  if (w < 2) {
    st16(&lred[w * 4096 + 0 * 32 + colw], acc0, g);
    st16(&lred[w * 4096 + 1 * 32 + colw], acc1, g);
    st16(&lred[w * 4096 + 2 * 32 + colw], acc2, g);
    st16(&lred[w * 4096 + 3 * 32 + colw], acc3, g);
  }
  __syncthreads();
  if (t < 32) {
    float d = 0.f;
#pragma unroll
    for (int w4 = 0; w4 < 4; w4++) d += dred[w4 * 32 + t];
    dpart[jc * NN + r0 + t] = d;
  }
  if (w >= 2) {
    ad16(&lred[(w - 2) * 4096 + 0 * 32 + colw], acc0, g);
    ad16(&lred[(w - 2) * 4096 + 1 * 32 + colw], acc1, g);
    ad16(&lred[(w - 2) * 4096 + 2 * 32 + colw], acc2, g);
    ad16(&lred[(w - 2) * 4096 + 3 * 32 + colw], acc3, g);
  }
  __syncthreads();

  // ---- write fp32 partial: sum the 2 bufs (16 floats/thread) ----
  const int flat = t * 16;  // row = t>>3, col = (t&7)*16
  float* pp = part + (size_t)jc * (NN * OUTF) + (size_t)r0 * OUTF + flat;
#pragma unroll
  for (int i = 0; i < 4; i++) {
    f32x4 pv = *(f32x4*)&lred[flat + 4 * i];
    pv += *(f32x4*)&lred[4096 + flat + 4 * i];
    *(f32x4*)(pp + 4 * i) = pv;
  }
}

// ---------------------------------------------------------------------------
// K4: combine 8 partials, divide by denom, elu, store.
// ---------------------------------------------------------------------------
__global__ __launch_bounds__(256) void gat_k4(
    const float* __restrict__ part, const float* __restrict__ dpart,
    float* __restrict__ out) {
  const int idx = blockIdx.x * 256 + threadIdx.x;
  const int e4 = idx * 4;
  const int i = e4 >> 7;
  f32x4 p = {0.f, 0.f, 0.f, 0.f};
  float d = 0.f;
#pragma unroll
  for (int jc = 0; jc < NJC; jc++) {
    p += *(const f32x4*)&part[(size_t)jc * (NN * OUTF) + e4];
    d += dpart[jc * NN + i];
  }
  d = fmaxf(d, 1e-30f);
  f32x4 r;
#pragma unroll
  for (int k = 0; k < 4; k++) {
    float v = p[k] / d;
    r[k] = (v > 0.f) ? v : expm1f(v);
  }
  *(f32x4*)&out[e4] = r;
}

extern "C" void kernel_launch(void* const* d_in, const int* in_sizes, int n_in,
                              void* d_out, int out_size, void* d_ws, size_t ws_size,
                              hipStream_t stream) {
  (void)in_sizes; (void)n_in; (void)out_size; (void)ws_size;
  const float* X  = (const float*)d_in[0];
  const int*  adj = (const int*)d_in[1];
  const float* W  = (const float*)d_in[2];
  const float* a  = (const float*)d_in[3];
  float* out = (float*)d_out;

  char* ws = (char*)d_ws;
  u16*   hbF   = (u16*)ws;                                  // 2 MB @ 0
  float* s1    = (float*)(ws + (2u << 20));                 // 32 KB
  float* s2    = (float*)(ws + (2u << 20) + (32u << 10));   // 32 KB
  float* bmax  = (float*)(ws + (2u << 20) + (64u << 10));   // 32 B
  float* E1    = (float*)(ws + (2u << 20) + (128u << 10));  // 32 KB
  float* E2    = (float*)(ws + (2u << 20) + (160u << 10));  // 32 KB
  float* dpart = (float*)(ws + (2u << 20) + (192u << 10));  // 256 KB
  float* part  = (float*)(ws + (4u << 20));                 // 32 MB @ 4M

  gat_k1<<<NN / 16, 256, 0, stream>>>(X, W, a, hbF, s1, s2);
  gat_k2<<<8, 256, 0, stream>>>(s2, bmax, E1, E2);
  gat_k3<<<256 * NJC, 256, 0, stream>>>(adj, hbF, s1, E1, E2, bmax, part, dpart);
  gat_k4<<<(NN * OUTF / 4) / 256, 256, 0, stream>>>(part, dpart, out);
}

// Round 12
// 116.171 us; speedup vs baseline: 1.2387x; 1.2387x over previous
//
#include <hip/hip_runtime.h>
#include <hip/hip_bf16.h>

#define NN   8192
#define INF_ 256
#define OUTF 128
#define SLOPE 0.2f
#define NC   4               // chunks of j per block
#define CHJ  2048            // j per chunk
#define NP   16              // pieces (= tiles) per chunk, 128 j each

typedef float f32x4  __attribute__((ext_vector_type(4)));
typedef float f32x16 __attribute__((ext_vector_type(16)));
typedef short bf16x8 __attribute__((ext_vector_type(8)));
typedef int   i32x4  __attribute__((ext_vector_type(4)));
typedef unsigned int u32;
typedef unsigned short u16;
typedef u16 u16x2 __attribute__((ext_vector_type(2)));

__device__ __forceinline__ u16 f2bf(float f) {
  return __builtin_bit_cast(u16, __float2bfloat16(f));
}

// j mapping: j = c*2048 + pr*128 + tt*8 + e   (c 0..3, pr 0..15, tt 0..15)
// pr = 2w + g (w = wave, g = lane>>5). hbF B-frag block index:
//   n = (c*8 + w)*16 + tt ; element (n, q, l, e) at ((n*4+q)*64 + l)*8 + e.
// Mask byte for (row, c, pr, tt) = mb[c&1][row*256 + (pr^(row&15))*16 + tt].

// ---------------------------------------------------------------------------
// K1: h = X @ W (fp32). 512 blocks x 16 rows. Writes hbF (B-frag order),
// s1, s2 (plain j order).
// ---------------------------------------------------------------------------
__global__ __launch_bounds__(256) void gat_k1(
    const float* __restrict__ X, const float* __restrict__ W,
    const float* __restrict__ a, u16* __restrict__ hbF,
    float* __restrict__ s1, float* __restrict__ s2) {
  __shared__ float xs[16 * INF_];
  const int t = threadIdx.x;
  const int r0 = blockIdx.x * 16;
  {
    const f32x4* src = (const f32x4*)(X + (size_t)r0 * INF_);
    f32x4* dst = (f32x4*)xs;
#pragma unroll
    for (int i = 0; i < 4; i++) dst[t + 256 * i] = src[t + 256 * i];
  }
  __syncthreads();
  const int cg = t & 31;
  const int rg = t >> 5;
  float acc[2][4];
#pragma unroll
  for (int i = 0; i < 2; i++)
#pragma unroll
    for (int j = 0; j < 4; j++) acc[i][j] = 0.f;

  for (int k = 0; k < INF_; k += 4) {
    f32x4 xv[2];
#pragma unroll
    for (int i = 0; i < 2; i++) xv[i] = *(const f32x4*)&xs[(rg * 2 + i) * INF_ + k];
#pragma unroll
    for (int kk = 0; kk < 4; kk++) {
      f32x4 wv = *(const f32x4*)&W[(k + kk) * OUTF + cg * 4];
#pragma unroll
      for (int i = 0; i < 2; i++)
#pragma unroll
        for (int j = 0; j < 4; j++) acc[i][j] = fmaf(xv[i][kk], wv[j], acc[i][j]);
    }
  }

  f32x4 a1v = *(const f32x4*)&a[cg * 4];
  f32x4 a2v = *(const f32x4*)&a[OUTF + cg * 4];
  float p1[2], p2[2];
#pragma unroll
  for (int i = 0; i < 2; i++) {
    p1[i] = acc[i][0] * a1v[0] + acc[i][1] * a1v[1] + acc[i][2] * a1v[2] + acc[i][3] * a1v[3];
    p2[i] = acc[i][0] * a2v[0] + acc[i][1] * a2v[1] + acc[i][2] * a2v[2] + acc[i][3] * a2v[3];
  }
#pragma unroll
  for (int m = 1; m < 32; m <<= 1) {
#pragma unroll
    for (int i = 0; i < 2; i++) {
      p1[i] += __shfl_xor(p1[i], m);
      p2[i] += __shfl_xor(p2[i], m);
    }
  }
  if (cg == 0) {
#pragma unroll
    for (int i = 0; i < 2; i++) {
      s1[r0 + rg * 2 + i] = p1[i];
      s2[r0 + rg * 2 + i] = p2[i];
    }
  }

  const int R0 = r0 + rg * 2;           // 2-aligned
  const int c  = R0 >> 11;
  const int pr = (R0 >> 7) & 15;
  const int tt = (R0 >> 3) & 15;
  const int e0 = R0 & 7;
  const int n  = (c * 8 + (pr >> 1)) * 16 + tt;
  const int lg = (pr & 1) * 32;
#pragma unroll
  for (int j = 0; j < 4; j++) {
    const int C = cg * 4 + j;
    u16x2 pk = {f2bf(acc[0][j]), f2bf(acc[1][j])};
    *(u16x2*)(hbF + ((size_t)(n * 4 + (C >> 5)) * 64 + lg + (C & 31)) * 8 + e0) = pk;
  }
}

// ---------------------------------------------------------------------------
// K2: E1 = exp(s2); E2 = exp(SLOPE*s2); bmax[block] = max chunk.
// ---------------------------------------------------------------------------
__global__ __launch_bounds__(256) void gat_k2(const float* __restrict__ s2,
                                              float* __restrict__ bmax,
                                              float* __restrict__ E1,
                                              float* __restrict__ E2) {
  __shared__ float sm[4];
  const int t = threadIdx.x;
  const int i = blockIdx.x * 256 + t;
  f32x4 v = ((const f32x4*)s2)[i];
  f32x4 e1, e2;
  float m = -1e30f;
#pragma unroll
  for (int k = 0; k < 4; k++) {
    m = fmaxf(m, v[k]);
    e1[k] = __expf(v[k]);
    e2[k] = __expf(SLOPE * v[k]);
  }
  ((f32x4*)E1)[i] = e1;
  ((f32x4*)E2)[i] = e2;
#pragma unroll
  for (int k = 1; k < 64; k <<= 1) m = fmaxf(m, __shfl_xor(m, k));
  if ((t & 63) == 0) sm[t >> 6] = m;
  __syncthreads();
  if (t == 0)
    bmax[blockIdx.x] = fmaxf(fmaxf(sm[0], sm[1]), fmaxf(sm[2], sm[3]));
}

// ---------------------------------------------------------------------------
// K3: one block per 32-row stripe, ALL 8192 j. Chunk-level double buffer:
// compute chunk c (masks in regs, loaded once per chunk) while streaming +
// packing chunk c+1 into the other LDS mask buffer. Zero barriers in the
// tile loop; ONE __syncthreads per chunk (all loads consumed => free drain).
// Full-row accumulation => no partials, epilogue divides + elu => out.
// 256 blocks x 512 threads (8 waves, 1 block/CU).
// ---------------------------------------------------------------------------
__device__ __forceinline__ void st16(float* dst, const f32x16& A, int g) {
#pragma unroll
  for (int r = 0; r < 16; r++) {
    const int dr = (r & 3) + 8 * (r >> 2) + 4 * g;
    dst[dr * 128] = A[r];
  }
}
__device__ __forceinline__ void ad16(float* dst, const f32x16& A, int g) {
#pragma unroll
  for (int r = 0; r < 16; r++) {
    const int dr = (r & 3) + 8 * (r >> 2) + 4 * g;
    dst[dr * 128] += A[r];
  }
}

__global__ __launch_bounds__(512, 2) void gat_k3(
    const int* __restrict__ adj, const u16* __restrict__ hbF,
    const float* __restrict__ s1g, const float* __restrict__ E1,
    const float* __restrict__ E2, const float* __restrict__ bmax,
    float* __restrict__ out) {
  __shared__ unsigned char mb[2][8192];  // mask double-buffer (2 x 32 x 256)
  __shared__ float lred[8192];           // 32 KB epilogue reduce
  __shared__ float dred[288];
  const int t = threadIdx.x;
  const int w = t >> 6;
  const int l = t & 63;
  const int r0 = blockIdx.x * 32;
  const int row = l & 31;
  const int g = l >> 5;
  const int pr = 2 * w + g;

  // ---- per-row constants ----
  float s2m = bmax[0];
#pragma unroll
  for (int k = 1; k < 8; k++) s2m = fmaxf(s2m, bmax[k]);
  const float s1r = s1g[r0 + row];
  float Mi = s1r + s2m;
  Mi = fmaxf(Mi, SLOPE * Mi);
  const float A = __expf(s1r - Mi);
  const float B = __expf(SLOPE * s1r - Mi);

  // ---- staging ids: thread (srow = t>>4, cl = t&15) = 32 contiguous B ----
  const int srow = t >> 4;
  const int cl = t & 15;
  const int* gsrc = adj + (size_t)(r0 + srow) * NN + cl * 8;
  const int wslot = ((0) ^ (srow & 15));  // recomputed per piece in macro

  i32x4 sA0, sA1, sB0, sB1;
#define LOADP(S0, S1, C, P)                                  \
  {                                                          \
    const int* p_ = gsrc + (C) * CHJ + (P) * 128;            \
    S0 = *(const i32x4*)(p_);                                \
    S1 = *(const i32x4*)(p_ + 4);                            \
  }
#define PACKP(S0, S1, P, NB)                                               \
  {                                                                        \
    unsigned b_ = 0;                                                       \
    _Pragma("unroll") for (int e_ = 0; e_ < 4; e_++) {                     \
      b_ |= (S0[e_] > 0 ? 1u : 0u) << e_;                                  \
      b_ |= (S1[e_] > 0 ? 1u : 0u) << (e_ + 4);                            \
    }                                                                      \
    mb[NB][srow * 256 + (((P) ^ (srow & 15)) << 4) + cl] = (unsigned char)b_; \
  }

  f32x16 acc0 = 0.f, acc1 = 0.f, acc2 = 0.f, acc3 = 0.f;
  float dsA = 0.f, dsB = 0.f;

#define COMPUTE(CC, TT, BMV)                                                 \
  {                                                                          \
    const unsigned b = ((unsigned)(BMV)[(TT) >> 2] >> (((TT)&3) * 8)) & 0xffu; \
    const u16* bqb = hbF + (size_t)(((CC)*8 + w) * 16 + (TT)) * 2048 + l * 8; \
    bf16x8 b0 = *(const bf16x8*)(bqb);                                       \
    bf16x8 b1 = *(const bf16x8*)(bqb + 512);                                 \
    bf16x8 b2 = *(const bf16x8*)(bqb + 1024);                                \
    bf16x8 b3 = *(const bf16x8*)(bqb + 1536);                                \
    const float* e1q = E1 + (CC)*CHJ + pr * 128 + (TT)*8;                    \
    const float* e2q = E2 + (CC)*CHJ + pr * 128 + (TT)*8;                    \
    f32x4 u0 = *(const f32x4*)(e1q);                                         \
    f32x4 u1 = *(const f32x4*)(e1q + 4);                                     \
    f32x4 v0 = *(const f32x4*)(e2q);                                         \
    f32x4 v1 = *(const f32x4*)(e2q + 4);                                     \
    const float uu[8] = {u0[0], u0[1], u0[2], u0[3], u1[0], u1[1], u1[2], u1[3]}; \
    const float vv[8] = {v0[0], v0[1], v0[2], v0[3], v1[0], v1[1], v1[2], v1[3]}; \
    u32 aw[4];                                                               \
    _Pragma("unroll") for (int e = 0; e < 8; e += 2) {                       \
      float pa = fmaxf(A * uu[e], B * vv[e]);                                \
      float pb = fmaxf(A * uu[e + 1], B * vv[e + 1]);                        \
      pa = (b & (1u << e)) ? pa : 0.f;                                       \
      pb = (b & (1u << (e + 1))) ? pb : 0.f;                                 \
      dsA += pa;                                                             \
      dsB += pb;                                                             \
      aw[e >> 1] = __builtin_amdgcn_perm(                                    \
          __builtin_bit_cast(u32, pb) + 0x8000u,                             \
          __builtin_bit_cast(u32, pa) + 0x8000u, 0x07060302u);               \
    }                                                                        \
    const bf16x8 af = __builtin_bit_cast(                                    \
        bf16x8, (i32x4){(int)aw[0], (int)aw[1], (int)aw[2], (int)aw[3]});    \
    acc0 = __builtin_amdgcn_mfma_f32_32x32x16_bf16(af, b0, acc0, 0, 0, 0);   \
    acc1 = __builtin_amdgcn_mfma_f32_32x32x16_bf16(af, b1, acc1, 0, 0, 0);   \
    acc2 = __builtin_amdgcn_mfma_f32_32x32x16_bf16(af, b2, acc2, 0, 0, 0);   \
    acc3 = __builtin_amdgcn_mfma_f32_32x32x16_bf16(af, b3, acc3, 0, 0, 0);   \
  }

  // ---- prologue: stream chunk 0 into mb[0] (2-deep pipeline) ----
  LOADP(sA0, sA1, 0, 0);
  LOADP(sB0, sB1, 0, 1);
#pragma unroll
  for (int p = 2; p < NP; p += 2) {
    PACKP(sA0, sA1, p - 2, 0);
    LOADP(sA0, sA1, 0, p);
    PACKP(sB0, sB1, p - 1, 0);
    LOADP(sB0, sB1, 0, p + 1);
  }
  PACKP(sA0, sA1, 14, 0);
  PACKP(sB0, sB1, 15, 0);
  __syncthreads();

  // ---- main: compute chunk c, stream chunk c+1 ----
  for (int c = 0; c < NC; c++) {
    const int cb = c & 1, nb = cb ^ 1;
    const i32x4 bmv =
        *(const i32x4*)&mb[cb][row * 256 + ((pr ^ (row & 15)) << 4)];
    const bool more = (c + 1 < NC);

#pragma unroll
    for (int th = 0; th < 8; th++) {
      const int t0 = th * 2, t1 = t0 + 1;
      if (more) {
        if (t0 >= 2) PACKP(sA0, sA1, t0 - 2, nb);
        LOADP(sA0, sA1, c + 1, t0);
      }
      COMPUTE(c, t0, bmv);
      if (more) {
        if (t1 >= 2) PACKP(sB0, sB1, t1 - 2, nb);
        LOADP(sB0, sB1, c + 1, t1);
      }
      COMPUTE(c, t1, bmv);
    }
    if (more) {
      PACKP(sA0, sA1, 14, nb);
      PACKP(sB0, sB1, 15, nb);
    }
    __syncthreads();
  }

  // ---- denominator ----
  float dsum = dsA + dsB;
  dsum += __shfl_xor(dsum, 32);
  if (l < 32) dred[w * 32 + l] = dsum;

  // ---- accumulator reduce across 8 waves into 2 LDS bufs ----
  const int colw = l & 31;
  if (w < 2) {
    st16(&lred[w * 4096 + 0 * 32 + colw], acc0, g);
    st16(&lred[w * 4096 + 1 * 32 + colw], acc1, g);
    st16(&lred[w * 4096 + 2 * 32 + colw], acc2, g);
    st16(&lred[w * 4096 + 3 * 32 + colw], acc3, g);
  }
  __syncthreads();
  if (t < 32) {
    float d = 0.f;
#pragma unroll
    for (int w8 = 0; w8 < 8; w8++) d += dred[w8 * 32 + t];
    dred[256 + t] = d;
  }
  if (w == 2 || w == 3) {
    ad16(&lred[(w - 2) * 4096 + 0 * 32 + colw], acc0, g);
    ad16(&lred[(w - 2) * 4096 + 1 * 32 + colw], acc1, g);
    ad16(&lred[(w - 2) * 4096 + 2 * 32 + colw], acc2, g);
    ad16(&lred[(w - 2) * 4096 + 3 * 32 + colw], acc3, g);
  }
  __syncthreads();
  if (w == 4 || w == 5) {
    ad16(&lred[(w - 4) * 4096 + 0 * 32 + colw], acc0, g);
    ad16(&lred[(w - 4) * 4096 + 1 * 32 + colw], acc1, g);
    ad16(&lred[(w - 4) * 4096 + 2 * 32 + colw], acc2, g);
    ad16(&lred[(w - 4) * 4096 + 3 * 32 + colw], acc3, g);
  }
  __syncthreads();
  if (w == 6 || w == 7) {
    ad16(&lred[(w - 6) * 4096 + 0 * 32 + colw], acc0, g);
    ad16(&lred[(w - 6) * 4096 + 1 * 32 + colw], acc1, g);
    ad16(&lred[(w - 6) * 4096 + 2 * 32 + colw], acc2, g);
    ad16(&lred[(w - 6) * 4096 + 3 * 32 + colw], acc3, g);
  }
  __syncthreads();

  // ---- finalize: sum 2 bufs, divide, elu, store out directly ----
  const float myden = fmaxf(dred[256 + (t >> 4)], 1e-30f);
  const int flat = t * 8;  // row = t>>4, col = (t&15)*8
  float o[8];
#pragma unroll
  for (int i = 0; i < 4; i++) {
    o[i] = lred[flat + i] + lred[4096 + flat + i];
    o[4 + i] = lred[flat + 4 + i] + lred[4096 + flat + 4 + i];
  }
  f32x4 ra, rb;
#pragma unroll
  for (int i = 0; i < 4; i++) {
    float va = o[i] / myden;
    float vb = o[4 + i] / myden;
    ra[i] = (va > 0.f) ? va : expm1f(va);
    rb[i] = (vb > 0.f) ? vb : expm1f(vb);
  }
  float* op = out + (size_t)(r0 + (t >> 4)) * OUTF + (t & 15) * 8;
  *(f32x4*)op = ra;
  *(f32x4*)(op + 4) = rb;
}

extern "C" void kernel_launch(void* const* d_in, const int* in_sizes, int n_in,
                              void* d_out, int out_size, void* d_ws, size_t ws_size,
                              hipStream_t stream) {
  (void)in_sizes; (void)n_in; (void)out_size; (void)ws_size;
  const float* X  = (const float*)d_in[0];
  const int*  adj = (const int*)d_in[1];
  const float* W  = (const float*)d_in[2];
  const float* a  = (const float*)d_in[3];
  float* out = (float*)d_out;

  char* ws = (char*)d_ws;
  u16*   hbF  = (u16*)ws;                                  // 2 MB @ 0
  float* s1   = (float*)(ws + (2u << 20));                 // 32 KB
  float* s2   = (float*)(ws + (2u << 20) + (32u << 10));   // 32 KB
  float* bmax = (float*)(ws + (2u << 20) + (64u << 10));   // 32 B
  float* E1   = (float*)(ws + (2u << 20) + (128u << 10));  // 32 KB
  float* E2   = (float*)(ws + (2u << 20) + (160u << 10));  // 32 KB

  gat_k1<<<NN / 16, 256, 0, stream>>>(X, W, a, hbF, s1, s2);
  gat_k2<<<8, 256, 0, stream>>>(s2, bmax, E1, E2);
  gat_k3<<<NN / 32, 512, 0, stream>>>(adj, hbF, s1, E1, E2, bmax, out);
}